// Round 6
// baseline (119.298 us; speedup 1.0000x reference)
//
#include <hip/hip_runtime.h>
#include <hip/hip_bf16.h>
#include <stdint.h>

#define BHN 64      // B*H
#define SEQ 2048
#define DH  64

typedef unsigned short u16;
typedef __attribute__((ext_vector_type(8))) short bf16x8;
typedef __attribute__((ext_vector_type(16))) float f32x16;

__device__ inline u16 f2bf(float x){
  union { float f; uint32_t u; } a; a.f = x;
  uint32_t u = a.u;
  uint32_t lsb = (u >> 16) & 1u;
  u += 0x7FFFu + lsb;          // RNE
  return (u16)(u >> 16);
}

__device__ inline float fast_exp2(float x){
#if __has_builtin(__builtin_amdgcn_exp2f)
  return __builtin_amdgcn_exp2f(x);
#else
  float r; asm("v_exp_f32 %0, %1" : "=v"(r) : "v"(x)); return r;
#endif
}

__device__ inline void gload_lds16(const void* g, void* l){
  __builtin_amdgcn_global_load_lds(
      (const __attribute__((address_space(1))) void*)g,
      (__attribute__((address_space(3))) void*)l, 16, 0, 0);
}

// ---------------- fused pre-pass kernel ----------------
// blocks 0..2047: build fragment-ordered KV tiles (as before)
// blocks 2048..2559: pack mask -> KEEP bits, pair-transposed
// Fusing saves one kernel-launch gap on the critical path.

__global__ __launch_bounds__(256) void prepass(const float* __restrict__ kf,
                                               const float* __restrict__ vf,
                                               const void* __restrict__ mraw,
                                               u16* __restrict__ tiles,
                                               uint32_t* __restrict__ mkp){
  int t = threadIdx.x;
  if (blockIdx.x < 2048){
    // ---- build_tiles ----
    __shared__ float sVf[64][65];
    int head = blockIdx.x >> 5;
    int kt   = blockIdx.x & 31;
    int k0   = kt * 64;

    // load V tile coalesced into LDS
    {
      int r = t >> 2;
      int dseg = (t & 3) * 16;
      const float* src = vf + ((int64_t)(head*SEQ + k0 + r))*DH + dseg;
      #pragma unroll
      for (int j = 0; j < 16; j += 4){
        float4 v = *(const float4*)(src + j);
        sVf[r][dseg+j+0] = v.x; sVf[r][dseg+j+1] = v.y;
        sVf[r][dseg+j+2] = v.z; sVf[r][dseg+j+3] = v.w;
      }
    }

    u16* outb = tiles + ((size_t)(head*32 + kt) << 13);  // 16KB = 8192 u16

    // K frags (no LDS dependency)
    #pragma unroll
    for (int i = 0; i < 2; i++){
      int cid = i*256 + t;          // 0..511 -> frags 0..7
      int f = cid >> 6;
      int l = cid & 63;
      int kh = f >> 2, ds = f & 3;
      int row = k0 + kh*32 + (l & 31);
      int dstart = ds*16 + (l >> 5)*8;
      const float* src = kf + ((int64_t)(head*SEQ + row))*DH + dstart;
      float4 a = *(const float4*)(src);
      float4 b = *(const float4*)(src + 4);
      union { u16 h[8]; uint4 v; } pk;
      pk.h[0]=f2bf(a.x); pk.h[1]=f2bf(a.y); pk.h[2]=f2bf(a.z); pk.h[3]=f2bf(a.w);
      pk.h[4]=f2bf(b.x); pk.h[5]=f2bf(b.y); pk.h[6]=f2bf(b.z); pk.h[7]=f2bf(b.w);
      *(uint4*)(outb + f*512 + l*8) = pk.v;
    }

    __syncthreads();

    // V frags from LDS (column reads, pad 65 -> conflict-free)
    #pragma unroll
    for (int i = 0; i < 2; i++){
      int cid = i*256 + t;          // 0..511 -> frags 8..15
      int g = cid >> 6;
      int l = cid & 63;
      int oh = g >> 2, ks = g & 3;
      int d  = oh*32 + (l & 31);
      int kk = ks*16 + (l >> 5)*8;
      union { u16 h[8]; uint4 v; } pk;
      #pragma unroll
      for (int j = 0; j < 8; j++) pk.h[j] = f2bf(sVf[kk+j][d]);
      *(uint4*)(outb + (8+g)*512 + l*8) = pk.v;
    }
  } else {
    // ---- pack_mask ----
    // word (row, wd) stored at mkp[((wd>>1)*SEQ + row)*2 + (wd&1)]
    // bit (r + 16*hi) of word w maps to k = w*32 + (r&3) + 8*(r>>2) + 4*hi
    __shared__ int sflag;
    const uint32_t* m32 = (const uint32_t*)mraw;
    if (t == 0) sflag = 0;
    __syncthreads();
    if (t < 64){
      uint32_t v = m32[t] | m32[t+64] | m32[t+128] | m32[t+192];
      if (v > 1u) atomicOr(&sflag, 1);   // bytes beyond LSB set => bool-byte layout
    }
    __syncthreads();
    bool isbool = (sflag != 0);
    int idx = (blockIdx.x - 2048)*256 + t;   // word index, 2048*64 total
    int row = idx >> 6;
    int wd  = idx & 63;
    uint32_t bits = 0;
    if (isbool){
      const uint8_t* mb = (const uint8_t*)mraw + (int64_t)row*SEQ + wd*32;
      uint4 a = ((const uint4*)mb)[0];
      uint4 b = ((const uint4*)mb)[1];
      uint32_t words[8] = {a.x,a.y,a.z,a.w,b.x,b.y,b.z,b.w};
      #pragma unroll
      for (int i = 0; i < 32; i++){
        int kl = (i&3) + 8*((i>>2)&3) + 4*(i>>4);
        uint32_t byte = (words[kl>>2] >> (8*(kl&3))) & 0xFFu;
        bits |= (byte ? 0u : 1u) << i;   // KEEP = !masked
      }
    } else {
      const uint32_t* mi = m32 + (int64_t)row*SEQ + wd*32;
      uint32_t words[32];
      #pragma unroll
      for (int j = 0; j < 32; j += 4){
        uint4 v = *(const uint4*)(mi + j);
        words[j+0]=v.x; words[j+1]=v.y; words[j+2]=v.z; words[j+3]=v.w;
      }
      #pragma unroll
      for (int i = 0; i < 32; i++){
        int kl = (i&3) + 8*((i>>2)&3) + 4*(i>>4);
        bits |= (words[kl] ? 0u : 1u) << i;
      }
    }
    mkp[((size_t)(wd >> 1)*SEQ + row)*2 + (wd & 1)] = bits;  // pair-transposed
  }
}

// ---------------- main flash-attention kernel ----------------
// OCCUPANCY EXPERIMENT (H1: latency-bound / TLP-starved at 4 waves/SIMD):
// 1024 blocks x 256 thr (4 waves). LDS exactly 32KB (2x16KB dbuf, NO sInv
// -- epilogue uses ds_bpermute, no LDS storage) -> 5 blocks/CU by LDS.
// Register diet: single live c-tile, exp2 in-place, post-exp AND mask,
// __launch_bounds__(256,5) caps the allocator at ~102 regs. If HW register
// quantum is fine-grained and the kernel fits, occupancy rises 16->20
// waves/CU (+25% TLP). If the quantum is coarse (64), this is neutral.
// 64-key step, counted vmcnt(5) + raw barriers (proven in r3-r5).
// Swapped QK^T: mfma(A=K, B=Q) -> lane holds P[q=lane&31][k-slice].

__global__ __launch_bounds__(256, 5) void attn_mfma(
    const float* __restrict__ qf, const u16* __restrict__ tiles,
    const uint32_t* __restrict__ mkp, float* __restrict__ out)
{
  // [2 bufs][16 frags][64 lanes][16B] = 32KB exactly
  __shared__ __align__(16) char lds[2*16384];

  int bid = blockIdx.x;
  int logical = (bid & 7)*128 + (bid >> 3);   // bijective XCD swizzle (1024%8==0)
  int head = logical >> 4;
  int q0   = (logical & 15) * 128;

  int t  = threadIdx.x;
  int w  = t >> 6;
  int l  = t & 63;
  int l31 = l & 31;
  int hi  = l >> 5;
  int hi16 = hi << 4;

  // Q B-frags (fp32 -> scaled bf16 in-kernel): lane holds Q[row][ds*16+hi*8+j]
  const float QS = 0.125f * 1.4426950408889634f;
  bf16x8 qfr[4];
  {
    const float* qrow = qf + ((size_t)(head*SEQ + q0 + w*32 + l31))*DH + hi*8;
    #pragma unroll
    for (int ds = 0; ds < 4; ds++){
      float4 a = *(const float4*)(qrow + ds*16);
      float4 b = *(const float4*)(qrow + ds*16 + 4);
      uint32_t u0, u1, u2, u3;
      asm("v_cvt_pk_bf16_f32 %0, %1, %2" : "=v"(u0) : "v"(a.x*QS), "v"(a.y*QS));
      asm("v_cvt_pk_bf16_f32 %0, %1, %2" : "=v"(u1) : "v"(a.z*QS), "v"(a.w*QS));
      asm("v_cvt_pk_bf16_f32 %0, %1, %2" : "=v"(u2) : "v"(b.x*QS), "v"(b.y*QS));
      asm("v_cvt_pk_bf16_f32 %0, %1, %2" : "=v"(u3) : "v"(b.z*QS), "v"(b.w*QS));
      union { uint32_t u[4]; bf16x8 h; } pk_;
      pk_.u[0]=u0; pk_.u[1]=u1; pk_.u[2]=u2; pk_.u[3]=u3;
      qfr[ds] = pk_.h;
    }
  }

  // mask base: uint2 index = kt64*SEQ + row
  const uint2* mbase = (const uint2*)mkp + (q0 + w*32 + l31);

  // staging: per 64-key step, wave w stages 4KB (frags 4w..4w+3), contiguous.
  const char* tb = (const char*)tiles + ((size_t)head << 19) + w*4096 + l*16;
  char* dwave = lds + w*4096;

  f32x16 O0 = {0,0,0,0,0,0,0,0,0,0,0,0,0,0,0,0};
  f32x16 O1 = {0,0,0,0,0,0,0,0,0,0,0,0,0,0,0,0};
  float ls0 = 0.f, ls1 = 0.f;

  const char* ldsL = lds + l*16;    // per-lane read base

  auto STAGE = [&](int kt64, int bufoff){
    const char* s_ = tb + ((size_t)kt64 << 14);
    char* d_ = dwave + bufoff;
    gload_lds16(s_,        d_);
    gload_lds16(s_ + 1024, d_ + 1024);
    gload_lds16(s_ + 2048, d_ + 2048);
    gload_lds16(s_ + 3072, d_ + 3072);
  };

  // prologue: stage tile 0, load mask 0
  STAGE(0, 0);
  asm volatile("" ::: "memory");          // keep stage-before-mask issue order
  uint2 mw2 = *mbase;

  int cur = 0;
  #pragma unroll 1
  for (int kt = 0; kt < 32; kt++){
    int nt = (kt < 31) ? (kt + 1) : 31;   // clamp: redundant re-stage on last iter
    STAGE(nt, cur ^ 16384);
    asm volatile("" ::: "memory");        // stage issues before mask load
    uint2 mnext = mbase[(size_t)nt*SEQ];

    // drain previous step's stage(+mask); keep this step's 5 in flight
    asm volatile("s_waitcnt vmcnt(5)" ::: "memory");
    __builtin_amdgcn_s_barrier();
    asm volatile("" ::: "memory");

    const char* lb = ldsL + cur;

    #pragma unroll
    for (int g = 0; g < 2; g++){
      uint32_t wsh = (g ? mw2.y : mw2.x) >> hi16;

      // QK^T into a single live c-tile
      f32x16 c = {0,0,0,0,0,0,0,0,0,0,0,0,0,0,0,0};
      __builtin_amdgcn_s_setprio(1);
      #pragma unroll
      for (int ds = 0; ds < 4; ds++){
        bf16x8 kfr = *(const bf16x8*)(lb + (4*g + ds)*1024);
        c = __builtin_amdgcn_mfma_f32_32x32x16_bf16(kfr, qfr[ds], c, 0, 0, 0);
      }
      __builtin_amdgcn_s_setprio(0);

      // softmax in-place: c[r] = keep & exp2(c[r])   (log2-scaled scores)
      #pragma unroll
      for (int r = 0; r < 16; r++){
        float pe = fast_exp2(c[r]);
        int32_t km;
        asm("v_bfe_i32 %0, %1, %2, 1" : "=v"(km) : "v"(wsh), "n"(r));
        c[r] = __uint_as_float(__float_as_uint(pe) & (uint32_t)km);
      }
      #pragma unroll
      for (int r = 0; r < 8; r++){ ls0 += c[r]; ls1 += c[r+8]; }

      // pack c -> PV A-frags: cvt_pk pairs, permlane32_swap redistributes halves
      bf16x8 pa0, pa1;
      {
        uint32_t A0, A1, B0, B1;
        asm("v_cvt_pk_bf16_f32 %0, %1, %2" : "=v"(A0) : "v"(c[0]), "v"(c[1]));
        asm("v_cvt_pk_bf16_f32 %0, %1, %2" : "=v"(A1) : "v"(c[2]), "v"(c[3]));
        asm("v_cvt_pk_bf16_f32 %0, %1, %2" : "=v"(B0) : "v"(c[4]), "v"(c[5]));
        asm("v_cvt_pk_bf16_f32 %0, %1, %2" : "=v"(B1) : "v"(c[6]), "v"(c[7]));
        asm("v_permlane32_swap_b32 %0, %1" : "+v"(A0), "+v"(B0));
        asm("v_permlane32_swap_b32 %0, %1" : "+v"(A1), "+v"(B1));
        union { uint32_t u[4]; bf16x8 h; } pk_;
        pk_.u[0] = A0; pk_.u[1] = A1; pk_.u[2] = B0; pk_.u[3] = B1;
        pa0 = pk_.h;
      }
      {
        uint32_t A0, A1, B0, B1;
        asm("v_cvt_pk_bf16_f32 %0, %1, %2" : "=v"(A0) : "v"(c[8]),  "v"(c[9]));
        asm("v_cvt_pk_bf16_f32 %0, %1, %2" : "=v"(A1) : "v"(c[10]), "v"(c[11]));
        asm("v_cvt_pk_bf16_f32 %0, %1, %2" : "=v"(B0) : "v"(c[12]), "v"(c[13]));
        asm("v_cvt_pk_bf16_f32 %0, %1, %2" : "=v"(B1) : "v"(c[14]), "v"(c[15]));
        asm("v_permlane32_swap_b32 %0, %1" : "+v"(A0), "+v"(B0));
        asm("v_permlane32_swap_b32 %0, %1" : "+v"(A1), "+v"(B1));
        union { uint32_t u[4]; bf16x8 h; } pk_;
        pk_.u[0] = A0; pk_.u[1] = A1; pk_.u[2] = B0; pk_.u[3] = B1;
        pa1 = pk_.h;
      }

      // PV: O[oh] += P-frag * V-frag
      __builtin_amdgcn_s_setprio(1);
      {
        bf16x8 v00 = *(const bf16x8*)(lb + (8  + 2*g)*1024);
        bf16x8 v01 = *(const bf16x8*)(lb + (9  + 2*g)*1024);
        bf16x8 v10 = *(const bf16x8*)(lb + (12 + 2*g)*1024);
        bf16x8 v11 = *(const bf16x8*)(lb + (13 + 2*g)*1024);
        O0 = __builtin_amdgcn_mfma_f32_32x32x16_bf16(pa0, v00, O0, 0, 0, 0);
        O0 = __builtin_amdgcn_mfma_f32_32x32x16_bf16(pa1, v01, O0, 0, 0, 0);
        O1 = __builtin_amdgcn_mfma_f32_32x32x16_bf16(pa0, v10, O1, 0, 0, 0);
        O1 = __builtin_amdgcn_mfma_f32_32x32x16_bf16(pa1, v11, O1, 0, 0, 0);
      }
      __builtin_amdgcn_s_setprio(0);
    }

    // WAR: all waves done reading buf[cur] before next iter's STAGE overwrites
    asm volatile("" ::: "memory");
    __builtin_amdgcn_s_barrier();
    asm volatile("" ::: "memory");

    mw2 = mnext;
    cur ^= 16384;
  }

  // epilogue: combine row-sum halves (permlane32_swap), then redistribute
  // 1/l across lanes with ds_bpermute (no LDS storage needed).
  float lt = ls0 + ls1;
  {
    uint32_t a = __float_as_uint(lt), b = a;
    asm("v_permlane32_swap_b32 %0, %1" : "+v"(a), "+v"(b));
    lt = __uint_as_float(a) + __uint_as_float(b);
  }
  float inv = 1.0f / lt;            // lane l holds inv for row (l&31)
  float* obase = out + ((size_t)(head*SEQ + q0 + w*32))*DH + l31;
  #pragma unroll
  for (int r = 0; r < 16; r++){
    int qrb = (r&3) + 8*(r>>2);            // row base (0..27)
    // source lane = qrb + 4*hi  -> byte index = (qrb<<2) + hi16
    int invr_i = __builtin_amdgcn_ds_bpermute((qrb << 2) + hi16,
                                              (int)__float_as_uint(inv));
    float invr = __uint_as_float((uint32_t)invr_i);
    int qr = qrb + 4*hi;                   // 0..31
    obase[(size_t)qr*DH]      = O0[r] * invr;
    obase[(size_t)qr*DH + 32] = O1[r] * invr;
  }
}

// ---------------- fallback (no workspace): naive but correct ----------------

__global__ __launch_bounds__(256) void attn_naive(
    const float* __restrict__ qf, const float* __restrict__ kf,
    const float* __restrict__ vf, const void* __restrict__ mraw,
    float* __restrict__ out)
{
  __shared__ float sq[64];
  __shared__ float sS[SEQ];
  __shared__ float redM[4], redS[4];
  __shared__ float sO[4][64];
  __shared__ int sflag;

  int bid = blockIdx.x;
  int bh = bid >> 11;
  int q  = bid & 2047;
  int t  = threadIdx.x;
  const uint32_t* m32 = (const uint32_t*)mraw;
  if (t == 0) sflag = 0;
  __syncthreads();
  if (t < 64){
    uint32_t v = m32[t] | m32[t+64] | m32[t+128] | m32[t+192];
    if (v > 1u) atomicOr(&sflag, 1);
  }
  if (t < 64) sq[t] = qf[((int64_t)bh*SEQ + q)*DH + t] * (0.125f*1.4426950408889634f);
  __syncthreads();
  bool isbool = (sflag != 0);

  float lmax = -3e38f;
  for (int k = t; k < SEQ; k += 256){
    bool masked = isbool ? (((const uint8_t*)mraw)[(int64_t)q*SEQ + k] != 0)
                         : (m32[(int64_t)q*SEQ + k] != 0);
    float s = -3e38f;
    if (!masked){
      const float* krow = kf + ((int64_t)bh*SEQ + k)*DH;
      float acc = 0.f;
      for (int d = 0; d < 64; d++) acc += sq[d]*krow[d];
      s = acc;
    }
    sS[k] = s;
    lmax = fmaxf(lmax, s);
  }
  for (int o = 32; o >= 1; o >>= 1) lmax = fmaxf(lmax, __shfl_xor(lmax, o));
  if ((t & 63) == 0) redM[t >> 6] = lmax;
  __syncthreads();
  float m = fmaxf(fmaxf(redM[0], redM[1]), fmaxf(redM[2], redM[3]));
  float lsum = 0.f;
  for (int k = t; k < SEQ; k += 256){
    float p = exp2f(sS[k] - m);
    sS[k] = p;
    lsum += p;
  }
  for (int o = 32; o >= 1; o >>= 1) lsum += __shfl_xor(lsum, o);
  if ((t & 63) == 0) redS[t >> 6] = lsum;
  __syncthreads();
  float lden = redS[0] + redS[1] + redS[2] + redS[3];

  float o = 0.f;
  int d = t & 63;
  int c = t >> 6;
  for (int k = c*512; k < (c+1)*512; k++)
    o += sS[k] * vf[((int64_t)bh*SEQ + k)*DH + d];
  sO[c][d] = o;
  __syncthreads();
  if (t < 64){
    float r = (sO[0][t] + sO[1][t] + sO[2][t] + sO[3][t]) / lden;
    out[((int64_t)bh*SEQ + q)*DH + t] = r;
  }
}

// ---------------- host ----------------

extern "C" void kernel_launch(void* const* d_in, const int* in_sizes, int n_in,
                              void* d_out, int out_size, void* d_ws, size_t ws_size,
                              hipStream_t stream)
{
  const float* qf = (const float*)d_in[0];
  const float* kf = (const float*)d_in[1];
  const float* vf = (const float*)d_in[2];
  const void*  mraw = d_in[3];
  float* out = (float*)d_out;

  size_t tilesB = (size_t)BHN*32*16384;           // 32 MB
  size_t need = tilesB + (size_t)SEQ*64*4 + 256;  // ~32.5 MB
  if (ws_size >= need){
    u16* tiles = (u16*)d_ws;
    uint32_t* mkp = (uint32_t*)((char*)d_ws + tilesB);
    hipLaunchKernelGGL(prepass,   dim3(2560), dim3(256), 0, stream, kf, vf, mraw, tiles, mkp);
    hipLaunchKernelGGL(attn_mfma, dim3(1024), dim3(256), 0, stream, qf, tiles, mkp, out);
  } else {
    hipLaunchKernelGGL(attn_naive, dim3(BHN*SEQ), dim3(256), 0, stream, qf, kf, vf, mraw, out);
  }
}

// Round 7
// 113.040 us; speedup vs baseline: 1.0554x; 1.0554x over previous
//
#include <hip/hip_runtime.h>
#include <hip/hip_bf16.h>
#include <stdint.h>

#define BHN 64      // B*H
#define SEQ 2048
#define DH  64

typedef unsigned short u16;
typedef __attribute__((ext_vector_type(8))) short bf16x8;
typedef __attribute__((ext_vector_type(16))) float f32x16;

__device__ inline u16 f2bf(float x){
  union { float f; uint32_t u; } a; a.f = x;
  uint32_t u = a.u;
  uint32_t lsb = (u >> 16) & 1u;
  u += 0x7FFFu + lsb;          // RNE
  return (u16)(u >> 16);
}

__device__ inline float fast_exp2(float x){
#if __has_builtin(__builtin_amdgcn_exp2f)
  return __builtin_amdgcn_exp2f(x);
#else
  float r; asm("v_exp_f32 %0, %1" : "=v"(r) : "v"(x)); return r;
#endif
}

__device__ inline void gload_lds16(const void* g, void* l){
  __builtin_amdgcn_global_load_lds(
      (const __attribute__((address_space(1))) void*)g,
      (__attribute__((address_space(3))) void*)l, 16, 0, 0);
}

// ---------------- fused pre-pass kernel ----------------
// blocks 0..2047: build fragment-ordered KV tiles
// blocks 2048..2559: pack mask -> KEEP bits, QUAD-transposed
// Fusing saves ~5us of launch gap (measured r5 vs r6 overhead split).

__global__ __launch_bounds__(256) void prepass(const float* __restrict__ kf,
                                               const float* __restrict__ vf,
                                               const void* __restrict__ mraw,
                                               u16* __restrict__ tiles,
                                               uint32_t* __restrict__ mkp){
  int t = threadIdx.x;
  if (blockIdx.x < 2048){
    // ---- build_tiles ----
    // tiles[head][kt64][frag 0..15][lane 0..63][16B], 16KB per (head,kt64).
    //  frag f<8  (K, kh=f>>2, ds=f&3):  lane l -> K[k0+kh*32+(l&31)][ds*16+(l>>5)*8 + 0..7]
    //  frag f>=8 (V, g=f-8, oh=g>>2, ks=g&3): lane l -> V[k0+ks*16+(l>>5)*8 + j][oh*32+(l&31)]
    __shared__ float sVf[64][65];
    int head = blockIdx.x >> 5;
    int kt   = blockIdx.x & 31;
    int k0   = kt * 64;

    // load V tile coalesced into LDS
    {
      int r = t >> 2;
      int dseg = (t & 3) * 16;
      const float* src = vf + ((int64_t)(head*SEQ + k0 + r))*DH + dseg;
      #pragma unroll
      for (int j = 0; j < 16; j += 4){
        float4 v = *(const float4*)(src + j);
        sVf[r][dseg+j+0] = v.x; sVf[r][dseg+j+1] = v.y;
        sVf[r][dseg+j+2] = v.z; sVf[r][dseg+j+3] = v.w;
      }
    }

    u16* outb = tiles + ((size_t)(head*32 + kt) << 13);  // 16KB = 8192 u16

    // K frags (no LDS dependency)
    #pragma unroll
    for (int i = 0; i < 2; i++){
      int cid = i*256 + t;          // 0..511 -> frags 0..7
      int f = cid >> 6;
      int l = cid & 63;
      int kh = f >> 2, ds = f & 3;
      int row = k0 + kh*32 + (l & 31);
      int dstart = ds*16 + (l >> 5)*8;
      const float* src = kf + ((int64_t)(head*SEQ + row))*DH + dstart;
      float4 a = *(const float4*)(src);
      float4 b = *(const float4*)(src + 4);
      union { u16 h[8]; uint4 v; } pk;
      pk.h[0]=f2bf(a.x); pk.h[1]=f2bf(a.y); pk.h[2]=f2bf(a.z); pk.h[3]=f2bf(a.w);
      pk.h[4]=f2bf(b.x); pk.h[5]=f2bf(b.y); pk.h[6]=f2bf(b.z); pk.h[7]=f2bf(b.w);
      *(uint4*)(outb + f*512 + l*8) = pk.v;
    }

    __syncthreads();

    // V frags from LDS (column reads, pad 65 -> conflict-free)
    #pragma unroll
    for (int i = 0; i < 2; i++){
      int cid = i*256 + t;          // 0..511 -> frags 8..15
      int g = cid >> 6;
      int l = cid & 63;
      int oh = g >> 2, ks = g & 3;
      int d  = oh*32 + (l & 31);
      int kk = ks*16 + (l >> 5)*8;
      union { u16 h[8]; uint4 v; } pk;
      #pragma unroll
      for (int j = 0; j < 8; j++) pk.h[j] = f2bf(sVf[kk+j][d]);
      *(uint4*)(outb + (8+g)*512 + l*8) = pk.v;
    }
  } else {
    // ---- pack_mask ----
    // word (row, wd) stored at mkp[((wd>>2)*SEQ + row)*4 + (wd&3)]
    // -> one aligned uint4 covers 128 keys for a row.
    // bit (r + 16*hi) of word w maps to k = w*32 + (r&3) + 8*(r>>2) + 4*hi
    __shared__ int sflag;
    const uint32_t* m32 = (const uint32_t*)mraw;
    if (t == 0) sflag = 0;
    __syncthreads();
    if (t < 64){
      uint32_t v = m32[t] | m32[t+64] | m32[t+128] | m32[t+192];
      if (v > 1u) atomicOr(&sflag, 1);   // bytes beyond LSB set => bool-byte layout
    }
    __syncthreads();
    bool isbool = (sflag != 0);
    int idx = (blockIdx.x - 2048)*256 + t;   // word index, 2048*64 total
    int row = idx >> 6;
    int wd  = idx & 63;
    uint32_t bits = 0;
    if (isbool){
      const uint8_t* mb = (const uint8_t*)mraw + (int64_t)row*SEQ + wd*32;
      uint4 a = ((const uint4*)mb)[0];
      uint4 b = ((const uint4*)mb)[1];
      uint32_t words[8] = {a.x,a.y,a.z,a.w,b.x,b.y,b.z,b.w};
      #pragma unroll
      for (int i = 0; i < 32; i++){
        int kl = (i&3) + 8*((i>>2)&3) + 4*(i>>4);
        uint32_t byte = (words[kl>>2] >> (8*(kl&3))) & 0xFFu;
        bits |= (byte ? 0u : 1u) << i;   // KEEP = !masked
      }
    } else {
      const uint32_t* mi = m32 + (int64_t)row*SEQ + wd*32;
      uint32_t words[32];
      #pragma unroll
      for (int j = 0; j < 32; j += 4){
        uint4 v = *(const uint4*)(mi + j);
        words[j+0]=v.x; words[j+1]=v.y; words[j+2]=v.z; words[j+3]=v.w;
      }
      #pragma unroll
      for (int i = 0; i < 32; i++){
        int kl = (i&3) + 8*((i>>2)&3) + 4*(i>>4);
        bits |= (words[kl] ? 0u : 1u) << i;
      }
    }
    mkp[((size_t)(wd >> 2)*SEQ + row)*4 + (wd & 3)] = bits;  // quad-transposed
  }
}

// ---------------- main flash-attention kernel ----------------
// 512 blocks x 512 thr (8 waves). Wave owns 32 q-rows (block: 256 rows).
// 128-key step, 2x32KB LDS dbuf, cooperative staging (4 gload_lds16/wave),
// counted vmcnt(5) + raw barriers. NEW: wave-rotated subgroup order
// (g2 = (gi + w)&3) -- de-phases the 8 waves' softmax-VALU and MFMA
// bursts inside each barrier interval so the pipes interleave across
// waves instead of alternating idle. Mask words rotated once per step
// via wave-uniform selects (no runtime indexing -> no scratch).
// Mask folded into MFMA C-init (keep ? 0 : -128; exp2(s-128)=0).
// NOTE: no register cap beyond 4 waves/EU (r6: capping to 102 regs
// serialized the schedule, 98->113us).
// Swapped QK^T: mfma(A=K, B=Q) -> lane holds P[q=lane&31][k-slice].

__global__ __launch_bounds__(512, 4) void attn_mfma(
    const float* __restrict__ qf, const u16* __restrict__ tiles,
    const uint32_t* __restrict__ mkp, float* __restrict__ out)
{
  // [2 bufs][2 kt64][16 frags][64 lanes][16B] = 64KB, + sInv 1KB
  __shared__ __align__(16) char lds[2*32768 + 1024];

  int bid = blockIdx.x;
  int logical = (bid & 7)*64 + (bid >> 3);   // bijective XCD swizzle (512%8==0)
  int head = logical >> 3;
  int q0   = (logical & 7) * 256;

  int t  = threadIdx.x;
  int w  = t >> 6;          // 0..7
  int l  = t & 63;
  int l31 = l & 31;
  int hi  = l >> 5;
  int hi16 = hi << 4;
  int wrot = w & 3;         // subgroup rotation amount (wave-uniform)

  // Q B-frags (fp32 -> scaled bf16 in-kernel): lane holds Q[row][ds*16+hi*8+j]
  const float QS = 0.125f * 1.4426950408889634f;
  bf16x8 qfr[4];
  {
    const float* qrow = qf + ((size_t)(head*SEQ + q0 + w*32 + l31))*DH + hi*8;
    #pragma unroll
    for (int ds = 0; ds < 4; ds++){
      float4 a = *(const float4*)(qrow + ds*16);
      float4 b = *(const float4*)(qrow + ds*16 + 4);
      uint32_t u0, u1, u2, u3;
      asm("v_cvt_pk_bf16_f32 %0, %1, %2" : "=v"(u0) : "v"(a.x*QS), "v"(a.y*QS));
      asm("v_cvt_pk_bf16_f32 %0, %1, %2" : "=v"(u1) : "v"(a.z*QS), "v"(a.w*QS));
      asm("v_cvt_pk_bf16_f32 %0, %1, %2" : "=v"(u2) : "v"(b.x*QS), "v"(b.y*QS));
      asm("v_cvt_pk_bf16_f32 %0, %1, %2" : "=v"(u3) : "v"(b.z*QS), "v"(b.w*QS));
      union { uint32_t u[4]; bf16x8 h; } pk_;
      pk_.u[0]=u0; pk_.u[1]=u1; pk_.u[2]=u2; pk_.u[3]=u3;
      qfr[ds] = pk_.h;
    }
  }

  // mask base: uint4 index = kt128*SEQ + row
  const uint4* mbase = (const uint4*)mkp + (q0 + w*32 + l31);

  // staging: per 128-key step, wave w stages 4KB at chunk w*4096, contiguous.
  const char* tb = (const char*)tiles + ((size_t)head << 19) + w*4096 + l*16;
  char* dwave = lds + w*4096;

  f32x16 O0 = {0,0,0,0,0,0,0,0,0,0,0,0,0,0,0,0};
  f32x16 O1 = {0,0,0,0,0,0,0,0,0,0,0,0,0,0,0,0};
  float ls0 = 0.f, ls1 = 0.f;

  const char* ldsL = lds + l*16;    // per-lane read base

  auto STAGE = [&](int kt128, int bufoff){
    const char* s_ = tb + ((size_t)kt128 << 15);
    char* d_ = dwave + bufoff;
    gload_lds16(s_,        d_);
    gload_lds16(s_ + 1024, d_ + 1024);
    gload_lds16(s_ + 2048, d_ + 2048);
    gload_lds16(s_ + 3072, d_ + 3072);
  };

  // prologue: stage tile 0, load mask 0
  STAGE(0, 0);
  asm volatile("" ::: "memory");          // keep stage-before-mask issue order
  uint4 mw4 = *mbase;

  int cur = 0;
  #pragma unroll 1
  for (int kt = 0; kt < 16; kt++){
    int nt = (kt < 15) ? (kt + 1) : 15;   // clamp: redundant re-stage on last iter
    STAGE(nt, cur ^ 32768);
    asm volatile("" ::: "memory");        // stage issues before mask load
    uint4 mnext = mbase[(size_t)nt*SEQ];

    // drain previous step's stage(+mask); keep this step's in flight
    asm volatile("s_waitcnt vmcnt(5)" ::: "memory");
    __builtin_amdgcn_s_barrier();
    asm volatile("" ::: "memory");

    // rotate mask words by wrot (wave-uniform selects; static indexing after)
    uint32_t a0 = mw4.x, a1 = mw4.y, a2 = mw4.z, a3 = mw4.w;
    uint32_t b0, b1, b2, b3;
    {
      uint32_t c0 = (wrot & 1) ? a1 : a0;
      uint32_t c1 = (wrot & 1) ? a2 : a1;
      uint32_t c2 = (wrot & 1) ? a3 : a2;
      uint32_t c3 = (wrot & 1) ? a0 : a3;
      b0 = (wrot & 2) ? c2 : c0;
      b1 = (wrot & 2) ? c3 : c1;
      b2 = (wrot & 2) ? c0 : c2;
      b3 = (wrot & 2) ? c1 : c3;
    }
    uint32_t bm[4]; bm[0]=b0; bm[1]=b1; bm[2]=b2; bm[3]=b3;   // static idx below

    #pragma unroll
    for (int gi = 0; gi < 4; gi++){
      // this wave's gi-th subgroup is global subgroup g2 = (gi + wrot) & 3
      // (address arithmetic on g2 is fine; bm[gi] is compile-time indexed)
      int g2 = (gi + wrot) & 3;
      int hh = g2 >> 1;            // which kt64 half
      int gg = g2 & 1;             // which 32-key half within it
      const char* lbK = ldsL + cur + hh*16384 + gg*4096;          // K frags
      const char* lbV = ldsL + cur + hh*16384 + 8192 + gg*2048;   // V frags
      uint32_t nsh = ~(bm[gi] >> hi16);

      // C-init does the masking: keep ? 0 : -128  (exp2(s-128) -> 0)
      f32x16 c;
      #pragma unroll
      for (int r = 0; r < 16; r++){
        int32_t km;
        asm("v_bfe_i32 %0, %1, %2, 1" : "=v"(km) : "v"(nsh), "n"(r));
        c[r] = __uint_as_float((uint32_t)km & 0xC3000000u);
      }

      // QK^T
      __builtin_amdgcn_s_setprio(1);
      #pragma unroll
      for (int ds = 0; ds < 4; ds++){
        bf16x8 kfr = *(const bf16x8*)(lbK + ds*1024);
        c = __builtin_amdgcn_mfma_f32_32x32x16_bf16(kfr, qfr[ds], c, 0, 0, 0);
      }
      __builtin_amdgcn_s_setprio(0);

      // softmax: p = exp2(s); masked entries ~0 from C-init
      float p[16];
      #pragma unroll
      for (int r = 0; r < 16; r++) p[r] = fast_exp2(c[r]);
      #pragma unroll
      for (int r = 0; r < 8; r++){ ls0 += p[r]; ls1 += p[r+8]; }

      // pack p -> PV A-frags: cvt_pk pairs + permlane32_swap
      bf16x8 pa0, pa1;
      {
        uint32_t A0, A1, B0, B1;
        asm("v_cvt_pk_bf16_f32 %0, %1, %2" : "=v"(A0) : "v"(p[0]), "v"(p[1]));
        asm("v_cvt_pk_bf16_f32 %0, %1, %2" : "=v"(A1) : "v"(p[2]), "v"(p[3]));
        asm("v_cvt_pk_bf16_f32 %0, %1, %2" : "=v"(B0) : "v"(p[4]), "v"(p[5]));
        asm("v_cvt_pk_bf16_f32 %0, %1, %2" : "=v"(B1) : "v"(p[6]), "v"(p[7]));
        asm("v_permlane32_swap_b32 %0, %1" : "+v"(A0), "+v"(B0));
        asm("v_permlane32_swap_b32 %0, %1" : "+v"(A1), "+v"(B1));
        union { uint32_t u[4]; bf16x8 h; } pk_;
        pk_.u[0] = A0; pk_.u[1] = A1; pk_.u[2] = B0; pk_.u[3] = B1;
        pa0 = pk_.h;
      }
      {
        uint32_t A0, A1, B0, B1;
        asm("v_cvt_pk_bf16_f32 %0, %1, %2" : "=v"(A0) : "v"(p[8]),  "v"(p[9]));
        asm("v_cvt_pk_bf16_f32 %0, %1, %2" : "=v"(A1) : "v"(p[10]), "v"(p[11]));
        asm("v_cvt_pk_bf16_f32 %0, %1, %2" : "=v"(B0) : "v"(p[12]), "v"(p[13]));
        asm("v_cvt_pk_bf16_f32 %0, %1, %2" : "=v"(B1) : "v"(p[14]), "v"(p[15]));
        asm("v_permlane32_swap_b32 %0, %1" : "+v"(A0), "+v"(B0));
        asm("v_permlane32_swap_b32 %0, %1" : "+v"(A1), "+v"(B1));
        union { uint32_t u[4]; bf16x8 h; } pk_;
        pk_.u[0] = A0; pk_.u[1] = A1; pk_.u[2] = B0; pk_.u[3] = B1;
        pa1 = pk_.h;
      }

      // PV: O[oh] += P-frag * V-frag
      __builtin_amdgcn_s_setprio(1);
      {
        bf16x8 v00 = *(const bf16x8*)(lbV);
        bf16x8 v01 = *(const bf16x8*)(lbV + 1024);
        bf16x8 v10 = *(const bf16x8*)(lbV + 4096);
        bf16x8 v11 = *(const bf16x8*)(lbV + 5120);
        O0 = __builtin_amdgcn_mfma_f32_32x32x16_bf16(pa0, v00, O0, 0, 0, 0);
        O0 = __builtin_amdgcn_mfma_f32_32x32x16_bf16(pa1, v01, O0, 0, 0, 0);
        O1 = __builtin_amdgcn_mfma_f32_32x32x16_bf16(pa0, v10, O1, 0, 0, 0);
        O1 = __builtin_amdgcn_mfma_f32_32x32x16_bf16(pa1, v11, O1, 0, 0, 0);
      }
      __builtin_amdgcn_s_setprio(0);
    }

    // WAR: all waves done reading buf[cur] before next iter's STAGE overwrites
    asm volatile("" ::: "memory");
    __builtin_amdgcn_s_barrier();
    asm volatile("" ::: "memory");

    mw4 = mnext;
    cur ^= 32768;
  }

  // epilogue: combine row-sum halves; redistribute 1/l via per-wave LDS
  float lt = ls0 + ls1;
  {
    uint32_t a = __float_as_uint(lt), b = a;
    asm("v_permlane32_swap_b32 %0, %1" : "+v"(a), "+v"(b));
    lt = __uint_as_float(a) + __uint_as_float(b);
  }
  float* sInv = (float*)(lds + 65536);
  if (hi == 0) sInv[w*32 + l31] = 1.0f / lt;
  // same-wave LDS write->read is in-order; no barrier needed
  float* obase = out + ((size_t)(head*SEQ + q0 + w*32))*DH + l31;
  #pragma unroll
  for (int r = 0; r < 16; r++){
    int qr = (r&3) + 8*(r>>2) + 4*hi;      // 0..31
    float inv = sInv[w*32 + qr];
    obase[(size_t)qr*DH]      = O0[r] * inv;
    obase[(size_t)qr*DH + 32] = O1[r] * inv;
  }
}

// ---------------- fallback (no workspace): naive but correct ----------------

__global__ __launch_bounds__(256) void attn_naive(
    const float* __restrict__ qf, const float* __restrict__ kf,
    const float* __restrict__ vf, const void* __restrict__ mraw,
    float* __restrict__ out)
{
  __shared__ float sq[64];
  __shared__ float sS[SEQ];
  __shared__ float redM[4], redS[4];
  __shared__ float sO[4][64];
  __shared__ int sflag;

  int bid = blockIdx.x;
  int bh = bid >> 11;
  int q  = bid & 2047;
  int t  = threadIdx.x;
  const uint32_t* m32 = (const uint32_t*)mraw;
  if (t == 0) sflag = 0;
  __syncthreads();
  if (t < 64){
    uint32_t v = m32[t] | m32[t+64] | m32[t+128] | m32[t+192];
    if (v > 1u) atomicOr(&sflag, 1);
  }
  if (t < 64) sq[t] = qf[((int64_t)bh*SEQ + q)*DH + t] * (0.125f*1.4426950408889634f);
  __syncthreads();
  bool isbool = (sflag != 0);

  float lmax = -3e38f;
  for (int k = t; k < SEQ; k += 256){
    bool masked = isbool ? (((const uint8_t*)mraw)[(int64_t)q*SEQ + k] != 0)
                         : (m32[(int64_t)q*SEQ + k] != 0);
    float s = -3e38f;
    if (!masked){
      const float* krow = kf + ((int64_t)bh*SEQ + k)*DH;
      float acc = 0.f;
      for (int d = 0; d < 64; d++) acc += sq[d]*krow[d];
      s = acc;
    }
    sS[k] = s;
    lmax = fmaxf(lmax, s);
  }
  for (int o = 32; o >= 1; o >>= 1) lmax = fmaxf(lmax, __shfl_xor(lmax, o));
  if ((t & 63) == 0) redM[t >> 6] = lmax;
  __syncthreads();
  float m = fmaxf(fmaxf(redM[0], redM[1]), fmaxf(redM[2], redM[3]));
  float lsum = 0.f;
  for (int k = t; k < SEQ; k += 256){
    float p = exp2f(sS[k] - m);
    sS[k] = p;
    lsum += p;
  }
  for (int o = 32; o >= 1; o >>= 1) lsum += __shfl_xor(lsum, o);
  if ((t & 63) == 0) redS[t >> 6] = lsum;
  __syncthreads();
  float lden = redS[0] + redS[1] + redS[2] + redS[3];

  float o = 0.f;
  int d = t & 63;
  int c = t >> 6;
  for (int k = c*512; k < (c+1)*512; k++)
    o += sS[k] * vf[((int64_t)bh*SEQ + k)*DH + d];
  sO[c][d] = o;
  __syncthreads();
  if (t < 64){
    float r = (sO[0][t] + sO[1][t] + sO[2][t] + sO[3][t]) / lden;
    out[((int64_t)bh*SEQ + q)*DH + t] = r;
  }
}

// ---------------- host ----------------

extern "C" void kernel_launch(void* const* d_in, const int* in_sizes, int n_in,
                              void* d_out, int out_size, void* d_ws, size_t ws_size,
                              hipStream_t stream)
{
  const float* qf = (const float*)d_in[0];
  const float* kf = (const float*)d_in[1];
  const float* vf = (const float*)d_in[2];
  const void*  mraw = d_in[3];
  float* out = (float*)d_out;

  size_t tilesB = (size_t)BHN*32*16384;           // 32 MB
  size_t need = tilesB + (size_t)SEQ*64*4 + 256;  // ~32.5 MB
  if (ws_size >= need){
    u16* tiles = (u16*)d_ws;
    uint32_t* mkp = (uint32_t*)((char*)d_ws + tilesB);
    hipLaunchKernelGGL(prepass,   dim3(2560), dim3(256), 0, stream, kf, vf, mraw, tiles, mkp);
    hipLaunchKernelGGL(attn_mfma, dim3(512),  dim3(512), 0, stream, qf, tiles, mkp, out);
  } else {
    hipLaunchKernelGGL(attn_naive, dim3(BHN*SEQ), dim3(256), 0, stream, qf, kf, vf, mraw, out);
  }
}

// Round 8
// 107.074 us; speedup vs baseline: 1.1142x; 1.0557x over previous
//
#include <hip/hip_runtime.h>
#include <hip/hip_bf16.h>
#include <stdint.h>

#define BHN 64      // B*H
#define SEQ 2048
#define DH  64

typedef unsigned short u16;
typedef __attribute__((ext_vector_type(8))) short bf16x8;
typedef __attribute__((ext_vector_type(16))) float f32x16;

__device__ inline u16 f2bf(float x){
  union { float f; uint32_t u; } a; a.f = x;
  uint32_t u = a.u;
  uint32_t lsb = (u >> 16) & 1u;
  u += 0x7FFFu + lsb;          // RNE
  return (u16)(u >> 16);
}

__device__ inline float fast_exp2(float x){
#if __has_builtin(__builtin_amdgcn_exp2f)
  return __builtin_amdgcn_exp2f(x);
#else
  float r; asm("v_exp_f32 %0, %1" : "=v"(r) : "v"(x)); return r;
#endif
}

__device__ inline void gload_lds16(const void* g, void* l){
  __builtin_amdgcn_global_load_lds(
      (const __attribute__((address_space(1))) void*)g,
      (__attribute__((address_space(3))) void*)l, 16, 0, 0);
}

// ---------------- fused pre-pass kernel ----------------
// blocks 0..2047: build fragment-ordered KV tiles
// blocks 2048..2559: pack mask -> KEEP bits, QUAD-transposed
// Fusing removes one kernel-launch gap from the critical path.

__global__ __launch_bounds__(256) void prepass(const float* __restrict__ kf,
                                               const float* __restrict__ vf,
                                               const void* __restrict__ mraw,
                                               u16* __restrict__ tiles,
                                               uint32_t* __restrict__ mkp){
  int t = threadIdx.x;
  if (blockIdx.x < 2048){
    // ---- build_tiles ----
    // tiles[head][kt64][frag 0..15][lane 0..63][16B], 16KB per (head,kt64).
    //  frag f<8  (K, kh=f>>2, ds=f&3):  lane l -> K[k0+kh*32+(l&31)][ds*16+(l>>5)*8 + 0..7]
    //  frag f>=8 (V, g=f-8, oh=g>>2, ks=g&3): lane l -> V[k0+ks*16+(l>>5)*8 + j][oh*32+(l&31)]
    __shared__ float sVf[64][65];
    int head = blockIdx.x >> 5;
    int kt   = blockIdx.x & 31;
    int k0   = kt * 64;

    // load V tile coalesced into LDS
    {
      int r = t >> 2;
      int dseg = (t & 3) * 16;
      const float* src = vf + ((int64_t)(head*SEQ + k0 + r))*DH + dseg;
      #pragma unroll
      for (int j = 0; j < 16; j += 4){
        float4 v = *(const float4*)(src + j);
        sVf[r][dseg+j+0] = v.x; sVf[r][dseg+j+1] = v.y;
        sVf[r][dseg+j+2] = v.z; sVf[r][dseg+j+3] = v.w;
      }
    }

    u16* outb = tiles + ((size_t)(head*32 + kt) << 13);  // 16KB = 8192 u16

    // K frags (no LDS dependency)
    #pragma unroll
    for (int i = 0; i < 2; i++){
      int cid = i*256 + t;          // 0..511 -> frags 0..7
      int f = cid >> 6;
      int l = cid & 63;
      int kh = f >> 2, ds = f & 3;
      int row = k0 + kh*32 + (l & 31);
      int dstart = ds*16 + (l >> 5)*8;
      const float* src = kf + ((int64_t)(head*SEQ + row))*DH + dstart;
      float4 a = *(const float4*)(src);
      float4 b = *(const float4*)(src + 4);
      union { u16 h[8]; uint4 v; } pk;
      pk.h[0]=f2bf(a.x); pk.h[1]=f2bf(a.y); pk.h[2]=f2bf(a.z); pk.h[3]=f2bf(a.w);
      pk.h[4]=f2bf(b.x); pk.h[5]=f2bf(b.y); pk.h[6]=f2bf(b.z); pk.h[7]=f2bf(b.w);
      *(uint4*)(outb + f*512 + l*8) = pk.v;
    }

    __syncthreads();

    // V frags from LDS (column reads, pad 65 -> conflict-free)
    #pragma unroll
    for (int i = 0; i < 2; i++){
      int cid = i*256 + t;          // 0..511 -> frags 8..15
      int g = cid >> 6;
      int l = cid & 63;
      int oh = g >> 2, ks = g & 3;
      int d  = oh*32 + (l & 31);
      int kk = ks*16 + (l >> 5)*8;
      union { u16 h[8]; uint4 v; } pk;
      #pragma unroll
      for (int j = 0; j < 8; j++) pk.h[j] = f2bf(sVf[kk+j][d]);
      *(uint4*)(outb + (8+g)*512 + l*8) = pk.v;
    }
  } else {
    // ---- pack_mask ----
    // word (row, wd) stored at mkp[((wd>>2)*SEQ + row)*4 + (wd&3)]
    // -> one aligned uint4 covers 128 keys for a row.
    // bit (r + 16*hi) of word w maps to k = w*32 + (r&3) + 8*(r>>2) + 4*hi
    __shared__ int sflag;
    const uint32_t* m32 = (const uint32_t*)mraw;
    if (t == 0) sflag = 0;
    __syncthreads();
    if (t < 64){
      uint32_t v = m32[t] | m32[t+64] | m32[t+128] | m32[t+192];
      if (v > 1u) atomicOr(&sflag, 1);   // bytes beyond LSB set => bool-byte layout
    }
    __syncthreads();
    bool isbool = (sflag != 0);
    int idx = (blockIdx.x - 2048)*256 + t;   // word index, 2048*64 total
    int row = idx >> 6;
    int wd  = idx & 63;
    uint32_t bits = 0;
    if (isbool){
      const uint8_t* mb = (const uint8_t*)mraw + (int64_t)row*SEQ + wd*32;
      uint4 a = ((const uint4*)mb)[0];
      uint4 b = ((const uint4*)mb)[1];
      uint32_t words[8] = {a.x,a.y,a.z,a.w,b.x,b.y,b.z,b.w};
      #pragma unroll
      for (int i = 0; i < 32; i++){
        int kl = (i&3) + 8*((i>>2)&3) + 4*(i>>4);
        uint32_t byte = (words[kl>>2] >> (8*(kl&3))) & 0xFFu;
        bits |= (byte ? 0u : 1u) << i;   // KEEP = !masked
      }
    } else {
      const uint32_t* mi = m32 + (int64_t)row*SEQ + wd*32;
      uint32_t words[32];
      #pragma unroll
      for (int j = 0; j < 32; j += 4){
        uint4 v = *(const uint4*)(mi + j);
        words[j+0]=v.x; words[j+1]=v.y; words[j+2]=v.z; words[j+3]=v.w;
      }
      #pragma unroll
      for (int i = 0; i < 32; i++){
        int kl = (i&3) + 8*((i>>2)&3) + 4*(i>>4);
        bits |= (words[kl] ? 0u : 1u) << i;
      }
    }
    mkp[((size_t)(wd >> 2)*SEQ + row)*4 + (wd & 3)] = bits;  // quad-transposed
  }
}

// ---------------- main flash-attention kernel ----------------
// EXACT r5 kernel (best measured: 98.0us) -- wave-rotation (r7) reverted.
// 512 blocks x 512 thr (8 waves). Wave owns 32 q-rows (block: 256 rows).
// 128-key step: 32KB tile double-buffered in LDS, staged cooperatively
// (4 gload_lds16/wave/step). Counted vmcnt(5) + raw barriers: only the
// previous step's stage loads drain; this step's stay in flight under
// compute. Mask: quad-transposed, one uint4 per lane per step.
// 4 subgroups of 32 keys between barriers, pair-interleaved
// (QK,QK,SM,PV,SM,PV per kt64-half).
// STRUCTURAL NOTE (rounds 1-7): q-parallelism = 64 heads x 2048 rows /
// 32 rows-per-wave = 4096 waves = exactly 4 waves/SIMD chip-wide --
// occupancy CANNOT rise without split-K (combine cost ~27us HBM, net
// loss). Schedule grafts (counted vmcnt, interleave, rotation, VALU
// cuts, MFMA-rowsum) all measured neutral-to-negative; this config is
// the plateau of the shared-LDS decomposition family at ~700 TF.
// Swapped QK^T: mfma(A=K, B=Q) -> lane holds P[q=lane&31][k-slice].

__global__ __launch_bounds__(512, 4) void attn_mfma(
    const float* __restrict__ qf, const u16* __restrict__ tiles,
    const uint32_t* __restrict__ mkp, float* __restrict__ out)
{
  // [2 bufs][2 kt64][16 frags][64 lanes][16B] = 64KB, + sInv 1KB
  __shared__ __align__(16) char lds[2*32768 + 1024];

  int bid = blockIdx.x;
  int logical = (bid & 7)*64 + (bid >> 3);   // bijective XCD swizzle (512%8==0)
  int head = logical >> 3;
  int q0   = (logical & 7) * 256;

  int t  = threadIdx.x;
  int w  = t >> 6;          // 0..7
  int l  = t & 63;
  int l31 = l & 31;
  int hi  = l >> 5;
  int hi16 = hi << 4;

  // Q B-frags (fp32 -> scaled bf16 in-kernel): lane holds Q[row][ds*16+hi*8+j]
  const float QS = 0.125f * 1.4426950408889634f;
  bf16x8 qfr[4];
  {
    const float* qrow = qf + ((size_t)(head*SEQ + q0 + w*32 + l31))*DH + hi*8;
    #pragma unroll
    for (int ds = 0; ds < 4; ds++){
      float4 a = *(const float4*)(qrow + ds*16);
      float4 b = *(const float4*)(qrow + ds*16 + 4);
      uint32_t u0, u1, u2, u3;
      asm("v_cvt_pk_bf16_f32 %0, %1, %2" : "=v"(u0) : "v"(a.x*QS), "v"(a.y*QS));
      asm("v_cvt_pk_bf16_f32 %0, %1, %2" : "=v"(u1) : "v"(a.z*QS), "v"(a.w*QS));
      asm("v_cvt_pk_bf16_f32 %0, %1, %2" : "=v"(u2) : "v"(b.x*QS), "v"(b.y*QS));
      asm("v_cvt_pk_bf16_f32 %0, %1, %2" : "=v"(u3) : "v"(b.z*QS), "v"(b.w*QS));
      union { uint32_t u[4]; bf16x8 h; } pk_;
      pk_.u[0]=u0; pk_.u[1]=u1; pk_.u[2]=u2; pk_.u[3]=u3;
      qfr[ds] = pk_.h;
    }
  }

  // mask base: uint4 index = kt128*SEQ + row
  const uint4* mbase = (const uint4*)mkp + (q0 + w*32 + l31);

  // staging: per 128-key step, wave w stages 4KB at chunk w*4096, contiguous.
  const char* tb = (const char*)tiles + ((size_t)head << 19) + w*4096 + l*16;
  char* dwave = lds + w*4096;

  f32x16 O0 = {0,0,0,0,0,0,0,0,0,0,0,0,0,0,0,0};
  f32x16 O1 = {0,0,0,0,0,0,0,0,0,0,0,0,0,0,0,0};
  float ls0 = 0.f, ls1 = 0.f;

  const char* ldsL = lds + l*16;    // per-lane read base

  auto STAGE = [&](int kt128, int bufoff){
    const char* s_ = tb + ((size_t)kt128 << 15);
    char* d_ = dwave + bufoff;
    gload_lds16(s_,        d_);
    gload_lds16(s_ + 1024, d_ + 1024);
    gload_lds16(s_ + 2048, d_ + 2048);
    gload_lds16(s_ + 3072, d_ + 3072);
  };

  // softmax + pack for one c-tile -> PV A-frags (pa0, pa1), accumulate ls
  auto SMPACK = [&](f32x16& c, bf16x8& pa0, bf16x8& pa1){
    float p[16];
    #pragma unroll
    for (int r = 0; r < 16; r++) p[r] = fast_exp2(c[r]);
    #pragma unroll
    for (int r = 0; r < 8; r++){ ls0 += p[r]; ls1 += p[r+8]; }
    {
      uint32_t A0, A1, B0, B1;
      asm("v_cvt_pk_bf16_f32 %0, %1, %2" : "=v"(A0) : "v"(p[0]), "v"(p[1]));
      asm("v_cvt_pk_bf16_f32 %0, %1, %2" : "=v"(A1) : "v"(p[2]), "v"(p[3]));
      asm("v_cvt_pk_bf16_f32 %0, %1, %2" : "=v"(B0) : "v"(p[4]), "v"(p[5]));
      asm("v_cvt_pk_bf16_f32 %0, %1, %2" : "=v"(B1) : "v"(p[6]), "v"(p[7]));
      asm("v_permlane32_swap_b32 %0, %1" : "+v"(A0), "+v"(B0));
      asm("v_permlane32_swap_b32 %0, %1" : "+v"(A1), "+v"(B1));
      union { uint32_t u[4]; bf16x8 h; } pk_;
      pk_.u[0] = A0; pk_.u[1] = A1; pk_.u[2] = B0; pk_.u[3] = B1;
      pa0 = pk_.h;
    }
    {
      uint32_t A0, A1, B0, B1;
      asm("v_cvt_pk_bf16_f32 %0, %1, %2" : "=v"(A0) : "v"(p[8]),  "v"(p[9]));
      asm("v_cvt_pk_bf16_f32 %0, %1, %2" : "=v"(A1) : "v"(p[10]), "v"(p[11]));
      asm("v_cvt_pk_bf16_f32 %0, %1, %2" : "=v"(B0) : "v"(p[12]), "v"(p[13]));
      asm("v_cvt_pk_bf16_f32 %0, %1, %2" : "=v"(B1) : "v"(p[14]), "v"(p[15]));
      asm("v_permlane32_swap_b32 %0, %1" : "+v"(A0), "+v"(B0));
      asm("v_permlane32_swap_b32 %0, %1" : "+v"(A1), "+v"(B1));
      union { uint32_t u[4]; bf16x8 h; } pk_;
      pk_.u[0] = A0; pk_.u[1] = A1; pk_.u[2] = B0; pk_.u[3] = B1;
      pa1 = pk_.h;
    }
  };

  // prologue: stage tile 0, load mask 0
  STAGE(0, 0);
  asm volatile("" ::: "memory");          // keep stage-before-mask issue order
  uint4 mw4 = *mbase;

  int cur = 0;
  #pragma unroll 1
  for (int kt = 0; kt < 16; kt++){
    int nt = (kt < 15) ? (kt + 1) : 15;   // clamp: redundant re-stage on last iter
    STAGE(nt, cur ^ 32768);
    asm volatile("" ::: "memory");        // stage issues before mask load
    uint4 mnext = mbase[(size_t)nt*SEQ];

    // drain previous step's stage(+mask); keep this step's in flight
    asm volatile("s_waitcnt vmcnt(5)" ::: "memory");
    __builtin_amdgcn_s_barrier();
    asm volatile("" ::: "memory");

    uint32_t mm[4] = {mw4.x, mw4.y, mw4.z, mw4.w};

    #pragma unroll
    for (int h = 0; h < 2; h++){
      const char* lb = ldsL + cur + h*16384;   // kt64-half base
      uint32_t nsh0 = ~(mm[2*h]   >> hi16);
      uint32_t nsh1 = ~(mm[2*h+1] >> hi16);

      // C-init does the masking: keep ? 0 : -128  (exp2(s-128) -> 0)
      f32x16 c0, c1;
      #pragma unroll
      for (int r = 0; r < 16; r++){
        int32_t km;
        asm("v_bfe_i32 %0, %1, %2, 1" : "=v"(km) : "v"(nsh0), "n"(r));
        c0[r] = __uint_as_float((uint32_t)km & 0xC3000000u);
      }
      #pragma unroll
      for (int r = 0; r < 16; r++){
        int32_t km;
        asm("v_bfe_i32 %0, %1, %2, 1" : "=v"(km) : "v"(nsh1), "n"(r));
        c1[r] = __uint_as_float((uint32_t)km & 0xC3000000u);
      }

      // QK(0) then QK(1): back-to-back MFMA bursts
      __builtin_amdgcn_s_setprio(1);
      #pragma unroll
      for (int ds = 0; ds < 4; ds++){
        bf16x8 kfr = *(const bf16x8*)(lb + ds*1024);
        c0 = __builtin_amdgcn_mfma_f32_32x32x16_bf16(kfr, qfr[ds], c0, 0, 0, 0);
      }
      #pragma unroll
      for (int ds = 0; ds < 4; ds++){
        bf16x8 kfr = *(const bf16x8*)(lb + (4 + ds)*1024);
        c1 = __builtin_amdgcn_mfma_f32_32x32x16_bf16(kfr, qfr[ds], c1, 0, 0, 0);
      }
      __builtin_amdgcn_s_setprio(0);

      // SM(0) while QK(1) completes
      bf16x8 pa0, pa1;
      SMPACK(c0, pa0, pa1);

      // PV(0)
      __builtin_amdgcn_s_setprio(1);
      {
        bf16x8 v00 = *(const bf16x8*)(lb + 8*1024);
        bf16x8 v01 = *(const bf16x8*)(lb + 9*1024);
        bf16x8 v10 = *(const bf16x8*)(lb + 12*1024);
        bf16x8 v11 = *(const bf16x8*)(lb + 13*1024);
        O0 = __builtin_amdgcn_mfma_f32_32x32x16_bf16(pa0, v00, O0, 0, 0, 0);
        O0 = __builtin_amdgcn_mfma_f32_32x32x16_bf16(pa1, v01, O0, 0, 0, 0);
        O1 = __builtin_amdgcn_mfma_f32_32x32x16_bf16(pa0, v10, O1, 0, 0, 0);
        O1 = __builtin_amdgcn_mfma_f32_32x32x16_bf16(pa1, v11, O1, 0, 0, 0);
      }
      __builtin_amdgcn_s_setprio(0);

      // SM(1) while PV(0) completes
      bf16x8 pb0, pb1;
      SMPACK(c1, pb0, pb1);

      // PV(1)
      __builtin_amdgcn_s_setprio(1);
      {
        bf16x8 v00 = *(const bf16x8*)(lb + 10*1024);
        bf16x8 v01 = *(const bf16x8*)(lb + 11*1024);
        bf16x8 v10 = *(const bf16x8*)(lb + 14*1024);
        bf16x8 v11 = *(const bf16x8*)(lb + 15*1024);
        O0 = __builtin_amdgcn_mfma_f32_32x32x16_bf16(pb0, v00, O0, 0, 0, 0);
        O0 = __builtin_amdgcn_mfma_f32_32x32x16_bf16(pb1, v01, O0, 0, 0, 0);
        O1 = __builtin_amdgcn_mfma_f32_32x32x16_bf16(pb0, v10, O1, 0, 0, 0);
        O1 = __builtin_amdgcn_mfma_f32_32x32x16_bf16(pb1, v11, O1, 0, 0, 0);
      }
      __builtin_amdgcn_s_setprio(0);
    }

    // WAR: all waves done reading buf[cur] before next iter's STAGE overwrites
    asm volatile("" ::: "memory");
    __builtin_amdgcn_s_barrier();
    asm volatile("" ::: "memory");

    mw4 = mnext;
    cur ^= 32768;
  }

  // epilogue: combine row-sum halves; redistribute 1/l via per-wave LDS
  float lt = ls0 + ls1;
  {
    uint32_t a = __float_as_uint(lt), b = a;
    asm("v_permlane32_swap_b32 %0, %1" : "+v"(a), "+v"(b));
    lt = __uint_as_float(a) + __uint_as_float(b);
  }
  float* sInv = (float*)(lds + 65536);
  if (hi == 0) sInv[w*32 + l31] = 1.0f / lt;
  // same-wave LDS write->read is in-order; no barrier needed
  float* obase = out + ((size_t)(head*SEQ + q0 + w*32))*DH + l31;
  #pragma unroll
  for (int r = 0; r < 16; r++){
    int qr = (r&3) + 8*(r>>2) + 4*hi;      // 0..31
    float inv = sInv[w*32 + qr];
    obase[(size_t)qr*DH]      = O0[r] * inv;
    obase[(size_t)qr*DH + 32] = O1[r] * inv;
  }
}

// ---------------- fallback (no workspace): naive but correct ----------------

__global__ __launch_bounds__(256) void attn_naive(
    const float* __restrict__ qf, const float* __restrict__ kf,
    const float* __restrict__ vf, const void* __restrict__ mraw,
    float* __restrict__ out)
{
  __shared__ float sq[64];
  __shared__ float sS[SEQ];
  __shared__ float redM[4], redS[4];
  __shared__ float sO[4][64];
  __shared__ int sflag;

  int bid = blockIdx.x;
  int bh = bid >> 11;
  int q  = bid & 2047;
  int t  = threadIdx.x;
  const uint32_t* m32 = (const uint32_t*)mraw;
  if (t == 0) sflag = 0;
  __syncthreads();
  if (t < 64){
    uint32_t v = m32[t] | m32[t+64] | m32[t+128] | m32[t+192];
    if (v > 1u) atomicOr(&sflag, 1);
  }
  if (t < 64) sq[t] = qf[((int64_t)bh*SEQ + q)*DH + t] * (0.125f*1.4426950408889634f);
  __syncthreads();
  bool isbool = (sflag != 0);

  float lmax = -3e38f;
  for (int k = t; k < SEQ; k += 256){
    bool masked = isbool ? (((const uint8_t*)mraw)[(int64_t)q*SEQ + k] != 0)
                         : (m32[(int64_t)q*SEQ + k] != 0);
    float s = -3e38f;
    if (!masked){
      const float* krow = kf + ((int64_t)bh*SEQ + k)*DH;
      float acc = 0.f;
      for (int d = 0; d < 64; d++) acc += sq[d]*krow[d];
      s = acc;
    }
    sS[k] = s;
    lmax = fmaxf(lmax, s);
  }
  for (int o = 32; o >= 1; o >>= 1) lmax = fmaxf(lmax, __shfl_xor(lmax, o));
  if ((t & 63) == 0) redM[t >> 6] = lmax;
  __syncthreads();
  float m = fmaxf(fmaxf(redM[0], redM[1]), fmaxf(redM[2], redM[3]));
  float lsum = 0.f;
  for (int k = t; k < SEQ; k += 256){
    float p = exp2f(sS[k] - m);
    sS[k] = p;
    lsum += p;
  }
  for (int o = 32; o >= 1; o >>= 1) lsum += __shfl_xor(lsum, o);
  if ((t & 63) == 0) redS[t >> 6] = lsum;
  __syncthreads();
  float lden = redS[0] + redS[1] + redS[2] + redS[3];

  float o = 0.f;
  int d = t & 63;
  int c = t >> 6;
  for (int k = c*512; k < (c+1)*512; k++)
    o += sS[k] * vf[((int64_t)bh*SEQ + k)*DH + d];
  sO[c][d] = o;
  __syncthreads();
  if (t < 64){
    float r = (sO[0][t] + sO[1][t] + sO[2][t] + sO[3][t]) / lden;
    out[((int64_t)bh*SEQ + q)*DH + t] = r;
  }
}

// ---------------- host ----------------

extern "C" void kernel_launch(void* const* d_in, const int* in_sizes, int n_in,
                              void* d_out, int out_size, void* d_ws, size_t ws_size,
                              hipStream_t stream)
{
  const float* qf = (const float*)d_in[0];
  const float* kf = (const float*)d_in[1];
  const float* vf = (const float*)d_in[2];
  const void*  mraw = d_in[3];
  float* out = (float*)d_out;

  size_t tilesB = (size_t)BHN*32*16384;           // 32 MB
  size_t need = tilesB + (size_t)SEQ*64*4 + 256;  // ~32.5 MB
  if (ws_size >= need){
    u16* tiles = (u16*)d_ws;
    uint32_t* mkp = (uint32_t*)((char*)d_ws + tilesB);
    hipLaunchKernelGGL(prepass,   dim3(2560), dim3(256), 0, stream, kf, vf, mraw, tiles, mkp);
    hipLaunchKernelGGL(attn_mfma, dim3(512),  dim3(512), 0, stream, qf, tiles, mkp, out);
  } else {
    hipLaunchKernelGGL(attn_naive, dim3(BHN*SEQ), dim3(256), 0, stream, qf, kf, vf, mraw, out);
  }
}